// Round 6
// baseline (82.039 us; speedup 1.0000x reference)
//
#include <hip/hip_runtime.h>
#include <hip/hip_bf16.h>
#include <stdint.h>

typedef __bf16 bf16_8 __attribute__((ext_vector_type(8)));
typedef float f32x4 __attribute__((ext_vector_type(4)));
typedef unsigned int u32;
typedef unsigned short u16;

// Problem dims (fixed): B=8, R=4, N=1024, D_IN=D_OUT=256.
// Inputs FP32 (per reference); internal GEMMs bf16 MFMA; output FP32.

__device__ __forceinline__ u16 f2b(float f) {
    return __builtin_bit_cast(u16, __float2bfloat16(f));
}

// 32-k rows: 4 chunks of 16B; chunk (row,g) at row*4 + (g ^ ((row>>1)&3)).
__device__ __forceinline__ u32 swz_off(u32 row, u32 g) {
    return (row * 4u + (g ^ ((row >> 1) & 3u))) * 16u;
}

// 64-k rows: 8 chunks of 16B; chunk (row,c) at row*8 + (c ^ ((row>>1)&7)).
// Frag reads (fixed c, 16 consecutive rows) stay <=2-way conflicted.
__device__ __forceinline__ u32 swz8(u32 row, u32 c) {
    return (row * 8u + (c ^ ((row >> 1) & 7u))) * 16u;
}

__device__ __forceinline__ void gload_lds16(const void* g, void* l) {
    __builtin_amdgcn_global_load_lds((const __attribute__((address_space(1))) void*)g,
                                     (__attribute__((address_space(3))) void*)l, 16, 0, 0);
}

// Compiler-only memory scheduling fence: pins VMEM issue-order regions so
// counted s_waitcnt vmcnt(N) bookkeeping is deterministic.
__device__ __forceinline__ void memfence_sched() { asm volatile("" ::: "memory"); }

__device__ __forceinline__ uint4 pack8(float4 a, float4 b) {
    uint4 pk;
    pk.x = (u32)f2b(a.x) | ((u32)f2b(a.y) << 16);
    pk.y = (u32)f2b(a.z) | ((u32)f2b(a.w) << 16);
    pk.z = (u32)f2b(b.x) | ((u32)f2b(b.y) << 16);
    pk.w = (u32)f2b(b.z) | ((u32)f2b(b.w) << 16);
    return pk;
}

// C[128x128] += A[128xK]*B[Kx128]; used by y_gemm only (small, ~3us).
template <int KSTEPS>
__device__ __forceinline__ void gemm_core(const u16* pA, u32 strideA,
                                          const u16* pB, u32 strideB,
                                          char* smem, f32x4 acc[4][4]) {
    const u32 t    = threadIdx.x;
    const u32 lane = t & 63u;
    const u32 w    = t >> 6;
    const u32 wm   = (w >> 1) * 64u;
    const u32 wn   = (w & 1u) * 64u;
    const u32 waveByte = (t & 192u) * 16u;
    const u32 row0 = t >> 2;
    const u32 gg0  = (t & 3u) ^ ((row0 >> 1) & 3u);
    const u32 row1 = row0 + 64u;
    const u32 gg1  = ((t + 256u) & 3u) ^ ((row1 >> 1) & 3u);
    const u32 fr = lane & 15u;
    const u32 fg = lane >> 4;

    gload_lds16(pA + (size_t)row0 * strideA + gg0 * 8u, smem + waveByte);
    gload_lds16(pA + (size_t)row1 * strideA + gg1 * 8u, smem + waveByte + 4096u);
    gload_lds16(pB + (size_t)row0 * strideB + gg0 * 8u, smem + 16384u + waveByte);
    gload_lds16(pB + (size_t)row1 * strideB + gg1 * 8u, smem + 16384u + waveByte + 4096u);
    asm volatile("s_waitcnt vmcnt(0)" ::: "memory");
    __builtin_amdgcn_s_barrier();

    u32 c = 0;
#pragma unroll 2
    for (int ks = 0; ks < KSTEPS; ++ks) {
        char* curA = smem + c * 8192u;
        char* curB = smem + 16384u + c * 8192u;
        if (ks + 1 < KSTEPS) {
            char* nxtA = smem + (c ^ 1u) * 8192u;
            char* nxtB = smem + 16384u + (c ^ 1u) * 8192u;
            const u32 k0 = (u32)(ks + 1) * 32u;
            gload_lds16(pA + (size_t)row0 * strideA + k0 + gg0 * 8u, nxtA + waveByte);
            gload_lds16(pA + (size_t)row1 * strideA + k0 + gg1 * 8u, nxtA + waveByte + 4096u);
            gload_lds16(pB + (size_t)row0 * strideB + k0 + gg0 * 8u, nxtB + waveByte);
            gload_lds16(pB + (size_t)row1 * strideB + k0 + gg1 * 8u, nxtB + waveByte + 4096u);
        }

        bf16_8 af[4], bfv[4];
#pragma unroll
        for (int mt = 0; mt < 4; ++mt) {
            uint4 v = *(const uint4*)(curA + swz_off(wm + (u32)mt * 16u + fr, fg));
            af[mt] = __builtin_bit_cast(bf16_8, v);
        }
#pragma unroll
        for (int nt = 0; nt < 4; ++nt) {
            uint4 v = *(const uint4*)(curB + swz_off(wn + (u32)nt * 16u + fr, fg));
            bfv[nt] = __builtin_bit_cast(bf16_8, v);
        }
#pragma unroll
        for (int mt = 0; mt < 4; ++mt)
#pragma unroll
            for (int nt = 0; nt < 4; ++nt)
                acc[mt][nt] = __builtin_amdgcn_mfma_f32_16x16x32_bf16(af[mt], bfv[nt],
                                                                      acc[mt][nt], 0, 0, 0);

        if (ks + 1 < KSTEPS) {
            asm volatile("s_waitcnt vmcnt(0)" ::: "memory");
            __builtin_amdgcn_s_barrier();
        }
        c ^= 1u;
    }
}

// textb = bf16(text), layout preserved [B,N,D_in]. 8 elems/thread.
__global__ __launch_bounds__(256) void text_cvt_kernel(const float* t, u16* tb) {
    const u32 i8 = blockIdx.x * 256u + threadIdx.x;  // 262144 total
    const float4 a = ((const float4*)t)[i8 * 2u];
    const float4 b = ((const float4*)t)[i8 * 2u + 1u];
    ((uint4*)tb)[i8] = pack8(a, b);
}

// Wt[r][dout][din] = bf16(W[r][din][dout])
__global__ __launch_bounds__(256) void wt_cvt_kernel(const float* W, u16* Wt) {
    const u32 idx = blockIdx.x * 256u + threadIdx.x;  // 262144 total
    const u32 r = idx >> 16, rem = idx & 65535u, dout = rem >> 8, din = rem & 255u;
    Wt[idx] = f2b(W[(r << 16) + (din << 8) + dout]);
}

// Yt[b,r,dout,j] = bf16( sum_din Wt[r,dout,din] * textb[b,j,din] )
__global__ __launch_bounds__(256) void y_gemm_kernel(const u16* Wt, const u16* textb,
                                                     u16* Yt) {
    __shared__ char smem[32768];
    const u32 bx = blockIdx.x;                 // 512 blocks: b(3)|r(2)|m(1)|n(3)
    const u32 n0 = (bx & 7u) * 128u;
    const u32 m0 = ((bx >> 3) & 1u) * 128u;
    const u32 r  = (bx >> 4) & 3u;
    const u32 b  = bx >> 6;
    const u16* pA = Wt + (size_t)r * 65536u + (size_t)m0 * 256u;
    const u16* pB = textb + (size_t)b * 262144u + (size_t)n0 * 256u;
    f32x4 acc[4][4];
#pragma unroll
    for (int i = 0; i < 4; ++i)
#pragma unroll
        for (int j = 0; j < 4; ++j) acc[i][j] = (f32x4){0.f, 0.f, 0.f, 0.f};
    gemm_core<8>(pA, 256u, pB, 256u, smem, acc);

    const u32 lane = threadIdx.x & 63u, w = threadIdx.x >> 6;
    const u32 wm = (w >> 1) * 64u, wn = (w & 1u) * 64u;
    const u32 rit = (lane >> 4) * 4u, cit = lane & 15u;  // C: row=(lane>>4)*4+reg
    u16* yb = Yt + (size_t)(b * 4u + r) * 262144u;
#pragma unroll
    for (int mt = 0; mt < 4; ++mt)
#pragma unroll
        for (int nt = 0; nt < 4; ++nt) {
            const u32 m = m0 + wm + (u32)mt * 16u + rit;
            const u32 n = n0 + wn + (u32)nt * 16u + cit;
#pragma unroll
            for (int rg = 0; rg < 4; ++rg)
                yb[(size_t)(m + (u32)rg) * 1024u + n] = f2b(acc[mt][nt][rg]);
        }
}

// partial[b,r,i,d] = inv[b,r,i] * sum_j adj[b,r,i,j]*Yt[b,r,d,j]
//
// 8-PHASE-STYLE SCHEDULE (T3+T4+T5, ported from the verified 256^2 template):
// Block = 128 i x 256 d (full), BK=64, 16 K-tiles, 512 thr = 8 waves (2Mx4N),
// wave-tile 64x64 (acc 4x4). Grid 256 = 8b x 4r x 8it -> 1 block/CU; adj read
// once; Yt panel L2-resident per XCD (2 MB) via XCD remap.
// Each K-tile = 4 phases; phase p: {frag ds_reads for nt=p + 1 staging issue}
// -> barrier -> setprio(1) -> 8 MFMA -> setprio(0) -> barrier. Counted vmcnt:
// per K-tile exactly 8 VMEM issues (4x A float4 FIRST, then 4x B gload_lds,
// all for tile kt+2). The A-pack (phase 3) implicitly drains A(kt+1)x4 (the
// 4 oldest); the end-of-tile explicit vmcnt(8) then drains exactly B(kt+1)x4,
// leaving kt's 8 in flight across the barrier. Never drains to 0 mid-loop.
// Invariant entering kt: bufA[kt&1]=A(kt), bufB[kt%3]=B(kt),
// rA[(kt+1)&1]=A(kt+1) regs; outstanding = {A(kt+1)x4, B(kt+1)x4}.
__global__ __launch_bounds__(512, 2) void adj_gemm_8ph(const float* adj, const u16* Yt,
                                                       float* partial) {
    __shared__ char smem[131072];
    char* bufA = smem;                     // 2 x 16384 (128 rows x 64k bf16)
    char* bufB = smem + 32768;             // 3 x 32768 (256 rows x 64k bf16)
    float* sInv = (float*)smem;            // aliases bufA[0]: only live in the
                                           // epilogue, after bufA[0]'s last read
                                           // (kt=14), ordered by __syncthreads.

    // XCD-contiguous bijective remap (256 = 8 XCDs x 32): XCD x gets batch
    // b = x entirely -> Yt[b] (2 MB) fits that XCD's 4 MB L2.
    const u32 raw = blockIdx.x;
    const u32 bx = (raw & 7u) * 32u + (raw >> 3);
    const u32 it = bx & 7u;
    const u32 r  = (bx >> 3) & 3u;
    const u32 b  = bx >> 5;
    const u32 i0 = it * 128u;

    const float* pA = adj + (size_t)(b * 4u + r) * 1048576u + (size_t)i0 * 1024u;
    const u16*   pB = Yt + (size_t)(b * 4u + r) * 262144u;

    const u32 t = threadIdx.x, lane = t & 63u, w = t >> 6;
    const u32 wm = (w >> 2) * 64u;        // 2 M-groups
    const u32 wn = (w & 3u) * 64u;        // 4 N-groups
    const u32 fr = lane & 15u, fg = lane >> 4;

    // A staging: thread t owns row sRow = t>>2, k-slice [(t&3)*16, +16) of each
    // K-tile: 4 float4 fp32 loads -> 2 uint4 bf16 ds_writes (pre-swizzled slots).
    const u32 sRow = t >> 2;
    const float* aBase = pA + (size_t)sRow * 1024u + (t & 3u) * 16u;
    const u32 aSw = (sRow >> 1) & 7u;
    const u32 aSlot0 = (sRow * 8u + (((t & 3u) * 2u) ^ aSw)) * 16u;
    const u32 aSlot1 = (sRow * 8u + (((t & 3u) * 2u + 1u) ^ aSw)) * 16u;

    // B staging: 2048 16B-chunks per K-tile, 4 gload_lds calls; call j stages
    // chunk j*512+t to linear LDS slot; global source pre-swizzled per row.
    u32 bOff[4];
#pragma unroll
    for (int j = 0; j < 4; ++j) {
        const u32 ci = (u32)j * 512u + t;
        const u32 row = ci >> 3, g = ci & 7u;
        bOff[j] = row * 1024u + (g ^ ((row >> 1) & 7u)) * 8u;
    }
    const u32 waveB = (t & 448u) * 16u;   // wave-uniform LDS byte base

    f32x4 acc[4][4];
#pragma unroll
    for (int i = 0; i < 4; ++i)
#pragma unroll
        for (int j = 0; j < 4; ++j) acc[i][j] = (f32x4){0.f, 0.f, 0.f, 0.f};

    float s0 = 0.f;
    float4 rA[2][4];

    auto loadA = [&](float4* dst, u32 kt) {
        const float* p = aBase + kt * 64u;
        dst[0] = *(const float4*)(p);
        dst[1] = *(const float4*)(p + 4);
        dst[2] = *(const float4*)(p + 8);
        dst[3] = *(const float4*)(p + 12);
    };
    auto packA = [&](const float4* rs, char* dst) {
        s0 += (rs[0].x + rs[0].y + rs[0].z + rs[0].w)
            + (rs[1].x + rs[1].y + rs[1].z + rs[1].w)
            + (rs[2].x + rs[2].y + rs[2].z + rs[2].w)
            + (rs[3].x + rs[3].y + rs[3].z + rs[3].w);
        *(uint4*)(dst + aSlot0) = pack8(rs[0], rs[1]);
        *(uint4*)(dst + aSlot1) = pack8(rs[2], rs[3]);
    };

    // One K-tile: 4 phases, each {reads+issue, barrier, MFMA cluster, barrier}.
    auto ktile = [&](char* bufAc, char* bufBc, char* bufAn, char* bufBn,
                     float4* rIssue, const float4* rPack, u32 ktIss,
                     bool doIssue, bool doPack, bool lastTile) {
        bf16_8 af[4][2];
#pragma unroll
        for (int p = 0; p < 4; ++p) {
            if (p == 0) {
                if (doIssue) { loadA(rIssue, ktIss); memfence_sched(); }
#pragma unroll
                for (int mt = 0; mt < 4; ++mt)
#pragma unroll
                    for (int ks = 0; ks < 2; ++ks) {
                        uint4 v = *(const uint4*)(bufAc +
                                   swz8(wm + (u32)mt * 16u + fr, (u32)ks * 4u + fg));
                        af[mt][ks] = __builtin_bit_cast(bf16_8, v);
                    }
            }
            if (doIssue) {
                gload_lds16(pB + bOff[p] + ktIss * 64u,
                            bufBn + (u32)p * 8192u + waveB);
                memfence_sched();
            }
            if (p == 3 && doPack) packA(rPack, bufAn);  // implicit wait drains A(kt+1)

            bf16_8 bf[2];
#pragma unroll
            for (int ks = 0; ks < 2; ++ks) {
                uint4 v = *(const uint4*)(bufBc +
                           swz8(wn + (u32)p * 16u + fr, (u32)ks * 4u + fg));
                bf[ks] = __builtin_bit_cast(bf16_8, v);
            }
            __builtin_amdgcn_s_barrier();
            __builtin_amdgcn_s_setprio(1);
#pragma unroll
            for (int mt = 0; mt < 4; ++mt)
#pragma unroll
                for (int ks = 0; ks < 2; ++ks)
                    acc[mt][p] = __builtin_amdgcn_mfma_f32_16x16x32_bf16(
                        af[mt][ks], bf[ks], acc[mt][p], 0, 0, 0);
            __builtin_amdgcn_s_setprio(0);
            if (p < 3) {
                __builtin_amdgcn_s_barrier();
            } else {
                if (doIssue)
                    asm volatile("s_waitcnt vmcnt(8) lgkmcnt(0)" ::: "memory");
                else if (doPack)
                    asm volatile("s_waitcnt vmcnt(0) lgkmcnt(0)" ::: "memory");
                else
                    asm volatile("s_waitcnt lgkmcnt(0)" ::: "memory");
                if (!lastTile) __builtin_amdgcn_s_barrier();
            }
        }
    };

    // ---- Prologue: A(0),B(0),A(1),B(1); pack A(0); leave {A(1),B(1)} in flight.
    loadA(rA[0], 0u);
    memfence_sched();
#pragma unroll
    for (int j = 0; j < 4; ++j)
        gload_lds16(pB + bOff[j], bufB + (u32)j * 8192u + waveB);
    memfence_sched();
    loadA(rA[1], 1u);
    memfence_sched();
#pragma unroll
    for (int j = 0; j < 4; ++j)
        gload_lds16(pB + bOff[j] + 64u, bufB + 32768u + (u32)j * 8192u + waveB);
    memfence_sched();
    packA(rA[0], bufA);   // implicit wait drains A(0)x4
    asm volatile("s_waitcnt vmcnt(8) lgkmcnt(0)" ::: "memory");  // drain B(0)x4
    __builtin_amdgcn_s_barrier();

    // ---- Main loop: kt = 0..13 (issue kt+2 <= 15) ----
#pragma unroll 2
    for (int kt = 0; kt < 14; ++kt) {
        const u32 cA = (u32)kt & 1u, nA = cA ^ 1u;
        ktile(bufA + cA * 16384u, bufB + (u32)(kt % 3) * 32768u,
              bufA + nA * 16384u, bufB + (u32)((kt + 2) % 3) * 32768u,
              rA[cA], rA[nA], (u32)(kt + 2), true, true, false);
    }
    // ---- Peel kt=14: no issues, pack A(15) ----
    ktile(bufA, bufB + 2u * 32768u, bufA + 16384u, bufB,
          rA[0], rA[1], 0u, false, true, false);
    // ---- Peel kt=15: compute only ----
    ktile(bufA + 16384u, bufB, bufA, bufB,
          rA[0], rA[1], 0u, false, false, true);

    // rowsum: 4 consecutive threads (t&3) hold k-slices of row sRow
    s0 += __shfl_down(s0, 2, 64);
    s0 += __shfl_down(s0, 1, 64);
    if ((t & 3u) == 0u) sInv[sRow] = (s0 == 0.f) ? 0.f : 1.f / s0;
    __syncthreads();

    float* pp = partial + (size_t)(b * 4u + r) * 262144u + (size_t)i0 * 256u;
#pragma unroll
    for (int mt = 0; mt < 4; ++mt)
#pragma unroll
        for (int rg = 0; rg < 4; ++rg) {
            const u32 mRow = wm + (u32)mt * 16u + fg * 4u + (u32)rg;
            const float inv = sInv[mRow];
#pragma unroll
            for (int nt = 0; nt < 4; ++nt)
                pp[(size_t)mRow * 256u + wn + (u32)nt * 16u + fr] = acc[mt][nt][rg] * inv;
        }
}

// out[b,i,d] = bias[d] + sum_r partial[b,r,i,d]
__global__ __launch_bounds__(256) void reduce_kernel(const float* partial,
                                                     const float* bias, float* out) {
    const u32 i4 = blockIdx.x * 256u + threadIdx.x;  // 524288 threads, 4 f32 each
    const u32 base = i4 * 4u;
    const u32 b = base >> 18;
    const u32 rem = base & 262143u;
    float4 s = ((const float4*)bias)[i4 & 63u];
#pragma unroll
    for (u32 r = 0; r < 4; ++r) {
        const float4 v = *(const float4*)(partial + (((size_t)(b * 4u + r)) << 18) + rem);
        s.x += v.x; s.y += v.y; s.z += v.z; s.w += v.w;
    }
    ((float4*)out)[i4] = s;
}

extern "C" void kernel_launch(void* const* d_in, const int* in_sizes, int n_in,
                              void* d_out, int out_size, void* d_ws, size_t ws_size,
                              hipStream_t stream) {
    const float* text = (const float*)d_in[0];  // [8,1024,256] fp32
    const float* adj  = (const float*)d_in[1];  // [8,4,1024,1024] fp32
    const float* wgt  = (const float*)d_in[2];  // [4,256,256] fp32
    const float* bias = (const float*)d_in[3];  // [256] fp32
    float* out = (float*)d_out;                 // [8,1024,256] fp32

    char* ws = (char*)d_ws;
    u16* Yt        = (u16*)ws;                      // 16 MB  bf16 [B,R,256,1024]
    u16* textb     = (u16*)(ws + 16777216u);        //  4 MB  bf16 [B,N,256]
    u16* Wt        = (u16*)(ws + 20971520u);        // 512 KB bf16 [R,256,256]
    float* partial = (float*)(ws + 21495808u);      // 32 MB  fp32 [B,R,N,256]

    text_cvt_kernel<<<1024, 256, 0, stream>>>(text, textb);
    wt_cvt_kernel<<<1024, 256, 0, stream>>>(wgt, Wt);
    y_gemm_kernel<<<512, 256, 0, stream>>>(Wt, textb, Yt);
    adj_gemm_8ph<<<256, 512, 0, stream>>>(adj, Yt, partial);
    reduce_kernel<<<2048, 256, 0, stream>>>(partial, bias, out);
}